// Round 17
// baseline (41.510 us; speedup 1.0000x reference)
//
#include <hip/hip_runtime.h>

// sites [4096,128] f32, consensus [512,128] f32
// out = softmax(-L1dist, axis=-1) -> [4096,512] f32
#define N_SITES 4096
#define M_CONS  512
#define DIM     128
#define RPB     4         // site rows per block
#define CH      8         // dims per chunk
#define NCH     16        // chunks
#define QPC     2         // 16B-quads per col per chunk (CH/4)

// Single fused kernel = R15 geometry with the UNHINTED allocator:
// __launch_bounds__(512,1) - the only configuration that has ever produced
// sane allocation (R9/R11/R12 -> 88 VGPR no spill; every min-waves>=2 hint
// -> 16-64 VGPR with spills or serialization: R6/7/8/10/15).
// 1024 blocks x 512 threads, 32 KB LDS (2 x 16 KB) -> LDS allows 4-5
// blocks/CU; occupancy now set by natural VGPR: <=64 -> 8 waves/SIMD,
// <=85 -> 6, else 4 (= R12 status quo). Live state ~12 regs (cv[8]+d[4]).
// Lane owns consensus column col==tid (validated R9-R16): cv[8] in VGPRs;
// sites block-uniform -> s_load -> SGPR operand; inner loop pure VALU
// (v_sub + v_add with abs modifier = the f32 floor, 2 ops/dim; packed f32
// has no abs/max on gfx950 - R14).
// Staging: global_load_lds w=16, pre-swizzled global source (#21), linear
// LDS dest. 32 B column stride -> swizzle key (c>>2)&1: bank-start residues
// 8*(c&3) + 4*(g^key) cover all 8 16B-slots evenly -> b128 extract at the
// 8-dword/bank structural floor.
// Softmax: block-local; dmat[4][512] overlay, waves 0-3 reduce rows 0-3
// (min + expsum via shuffles), broadcast red, coalesced stores.
__global__ __launch_bounds__(512, 1) void fused_kernel(const float* __restrict__ sites,
                                                       const float* __restrict__ cons,
                                                       float* __restrict__ out) {
    __shared__ __align__(16) float lds[8192];    // 32 KB = 2 x 16 KB buffers

    const int tid = threadIdx.x;
    const int bid = blockIdx.x;
    const int r0  = bid * RPB;

    // ---- prologue: DMA chunk 0 into buffer 0 (1024 slots, 2 per thread)
#pragma unroll
    for (int c = 0; c < 2; c++) {
        const int f = c * 512 + tid;             // slot 0..1023
        const int r = f >> 1, q = f & 1;
        const float* gsrc = cons + (size_t)r * DIM + ((q ^ ((r >> 2) & 1)) << 2);
        __builtin_amdgcn_global_load_lds(
            (const __attribute__((address_space(1))) void*)gsrc,
            (__attribute__((address_space(3))) void*)&lds[f * 4], 16, 0, 0);
    }
    __syncthreads();

    float d[RPB];
#pragma unroll
    for (int i = 0; i < RPB; i++) d[i] = 0.f;

    const float* srow = sites + (size_t)r0 * DIM;
    const int key = (tid >> 2) & 1;

#pragma unroll
    for (int h = 0; h < NCH; h++) {
        float* cur = &lds[(h & 1) * 4096];       // compile-time (full unroll)
        float* nxt = &lds[((h + 1) & 1) * 4096];

        // ---- extract my column (2 x ds_read_b128, 8 dwords/bank = floor)
        float cv[CH];
#pragma unroll
        for (int g = 0; g < QPC; g++) {
            float4 v = *(const float4*)&cur[tid * CH + ((g ^ key) << 2)];
            cv[4*g+0] = v.x; cv[4*g+1] = v.y; cv[4*g+2] = v.z; cv[4*g+3] = v.w;
        }

        // ---- issue next chunk's DMA (zero register cost, lands under compute)
        if (h < NCH - 1) {
#pragma unroll
            for (int c = 0; c < 2; c++) {
                const int f = c * 512 + tid;
                const int r = f >> 1, q = f & 1;
                const float* gsrc = cons + (size_t)r * DIM + (h + 1) * CH
                                         + ((q ^ ((r >> 2) & 1)) << 2);
                __builtin_amdgcn_global_load_lds(
                    (const __attribute__((address_space(1))) void*)gsrc,
                    (__attribute__((address_space(3))) void*)&nxt[f * 4], 16, 0, 0);
            }
        }

        // ---- pure-VALU accumulation: 4 rows x 8 dims (srow -> SGPR)
#pragma unroll
        for (int rr = 0; rr < RPB; rr++) {
#pragma unroll
            for (int k = 0; k < CH; k++)
                d[rr] += fabsf(srow[rr * DIM + h * CH + k] - cv[k]);
        }

        __syncthreads();                         // drains vmcnt -> nxt ready
    }

    // ---- block-local softmax: dmat[4][512] overlay (8 KB of buffer 0)
#pragma unroll
    for (int rr = 0; rr < RPB; rr++)
        lds[rr * 512 + tid] = d[rr];             // consecutive lanes: free
    __syncthreads();

    const int wv = tid >> 6;
    const int ln = tid & 63;
    if (wv < RPB) {                              // waves 0-3 reduce rows 0-3
        const float* p = &lds[wv * 512 + ln * 8];
        float4 a = *(const float4*)(p);
        float4 b = *(const float4*)(p + 4);
        float m = fminf(fminf(fminf(a.x, a.y), fminf(a.z, a.w)),
                        fminf(fminf(b.x, b.y), fminf(b.z, b.w)));
#pragma unroll
        for (int off = 32; off > 0; off >>= 1) m = fminf(m, __shfl_xor(m, off));
        float s = ((__expf(m - a.x) + __expf(m - a.y)) + (__expf(m - a.z) + __expf(m - a.w)))
                + ((__expf(m - b.x) + __expf(m - b.y)) + (__expf(m - b.z) + __expf(m - b.w)));
#pragma unroll
        for (int off = 32; off > 0; off >>= 1) s += __shfl_xor(s, off);
        if (ln == 0) {
            lds[2048 + wv] = m;                  // row min  [4]
            lds[2056 + wv] = 1.f / s;            // row inv-sum [4]
        }
    }
    __syncthreads();

    // ---- final: exp(mn - d) * inv from registers, coalesced 2 KB stores
#pragma unroll
    for (int rr = 0; rr < RPB; rr++) {
        float mn  = lds[2048 + rr];              // broadcast (same address)
        float inv = lds[2056 + rr];
        out[(size_t)(r0 + rr) * M_CONS + tid] = __expf(mn - d[rr]) * inv;
    }
}

extern "C" void kernel_launch(void* const* d_in, const int* in_sizes, int n_in,
                              void* d_out, int out_size, void* d_ws, size_t ws_size,
                              hipStream_t stream) {
    const float* sites = (const float*)d_in[0];
    const float* cons  = (const float*)d_in[1];
    float* out = (float*)d_out;

    fused_kernel<<<N_SITES / RPB, 512, 0, stream>>>(sites, cons, out);  // 1024 blocks
}

// Round 18
// 21.659 us; speedup vs baseline: 1.9166x; 1.9166x over previous
//
#include <hip/hip_runtime.h>

// sites [4096,128] f32, consensus [512,128] f32
// out = softmax(-L1dist, axis=-1) -> [4096,512] f32
#define N_SITES 4096
#define M_CONS  512
#define DIM     128
#define RPB     8         // site rows per block
#define CH      16        // dims per chunk
#define NCH     8         // chunks
#define QPC     4         // 16B-quads per col per chunk (CH/4)

// FINAL = R12 (session best, 21.26 us). Single fused kernel.
// 512 blocks x 512 threads, 64 KB LDS (2 x 32 KB) -> 2 blocks/CU
// = 16 waves/CU = 4 waves/SIMD.
// __launch_bounds__(512,1): the ONLY config producing sane allocation
// (88 VGPR, no spill). Any min-waves>=2 hint OR a too-small live set (CH=8)
// collapses the allocator to 16-64 VGPR with spills/serialization
// (R6/7/8/10/15/17).
// Lane owns consensus column col==tid: cv[16] in VGPRs; site elements are
// block-uniform -> s_load -> SGPR operand; inner loop is pure VALU
// (v_sub + v_add with free abs modifier = 2 ops/dim, the f32 floor; packed
// f32 has no abs/max on gfx950 - R14).
// Staging: chunk h+1 DMA'd global->LDS (global_load_lds w=16) with
// PRE-SWIZZLED global source (#21 both-sides rule): slot q of col r holds
// global quad q^((r>>1)&3); LDS dest linear as required; extract applies the
// same XOR -> full 32-bank spread at the b128 structural floor.
// Per-chunk __syncthreads doubles as the vmcnt drain (barriers are NOT the
// cost - R13 zero-barrier variant was neutral; phase rotation R16 neutral).
// Softmax: block-local; dmat[8][512] overlay, wave-per-row shuffle reduce
// (min + expsum), broadcast red scalars, coalesced 2 KB stores.
__global__ __launch_bounds__(512, 1) void fused_kernel(const float* __restrict__ sites,
                                                       const float* __restrict__ cons,
                                                       float* __restrict__ out) {
    __shared__ __align__(16) float lds[16384];   // 64 KB = 2 x 32 KB buffers

    const int tid = threadIdx.x;
    const int bid = blockIdx.x;
    const int r0  = bid * RPB;

    // ---- prologue: DMA chunk 0 into buffer 0 (2048 slots, 4 per thread)
#pragma unroll
    for (int c = 0; c < 4; c++) {
        const int f = c * 512 + tid;             // slot 0..2047
        const int r = f >> 2, q = f & 3;
        const float* gsrc = cons + (size_t)r * DIM + ((q ^ ((r >> 1) & 3)) << 2);
        __builtin_amdgcn_global_load_lds(
            (const __attribute__((address_space(1))) void*)gsrc,
            (__attribute__((address_space(3))) void*)&lds[f * 4], 16, 0, 0);
    }
    __syncthreads();

    float d[RPB];
#pragma unroll
    for (int i = 0; i < RPB; i++) d[i] = 0.f;

    const float* srow = sites + (size_t)r0 * DIM;

#pragma unroll
    for (int h = 0; h < NCH; h++) {
        float* cur = &lds[(h & 1) * 8192];       // compile-time (full unroll)
        float* nxt = &lds[((h + 1) & 1) * 8192];

        // ---- extract my column (4 x ds_read_b128, full-bank spread)
        float cv[CH];
#pragma unroll
        for (int g = 0; g < QPC; g++) {
            float4 v = *(const float4*)&cur[tid * CH + ((g ^ ((tid >> 1) & 3)) << 2)];
            cv[4*g+0] = v.x; cv[4*g+1] = v.y; cv[4*g+2] = v.z; cv[4*g+3] = v.w;
        }

        // ---- issue next chunk's DMA (zero register cost, lands under compute)
        if (h < NCH - 1) {
#pragma unroll
            for (int c = 0; c < 4; c++) {
                const int f = c * 512 + tid;
                const int r = f >> 2, q = f & 3;
                const float* gsrc = cons + (size_t)r * DIM + (h + 1) * CH
                                         + ((q ^ ((r >> 1) & 3)) << 2);
                __builtin_amdgcn_global_load_lds(
                    (const __attribute__((address_space(1))) void*)gsrc,
                    (__attribute__((address_space(3))) void*)&nxt[f * 4], 16, 0, 0);
            }
        }

        // ---- pure-VALU accumulation: 8 rows x 16 dims (srow -> SGPR)
#pragma unroll
        for (int rr = 0; rr < RPB; rr++) {
#pragma unroll
            for (int k = 0; k < CH; k++)
                d[rr] += fabsf(srow[rr * DIM + h * CH + k] - cv[k]);
        }

        __syncthreads();                         // drains vmcnt -> nxt ready
    }

    // ---- block-local softmax: dmat[8][512] overlay (16 KB of buffer 0)
#pragma unroll
    for (int rr = 0; rr < RPB; rr++)
        lds[rr * 512 + tid] = d[rr];             // consecutive lanes: free
    __syncthreads();

    const int wv = tid >> 6;                     // wave wv reduces row wv
    const int ln = tid & 63;
    {
        const float* p = &lds[wv * 512 + ln * 8];
        float4 a = *(const float4*)(p);
        float4 b = *(const float4*)(p + 4);
        float m = fminf(fminf(fminf(a.x, a.y), fminf(a.z, a.w)),
                        fminf(fminf(b.x, b.y), fminf(b.z, b.w)));
#pragma unroll
        for (int off = 32; off > 0; off >>= 1) m = fminf(m, __shfl_xor(m, off));
        float s = ((__expf(m - a.x) + __expf(m - a.y)) + (__expf(m - a.z) + __expf(m - a.w)))
                + ((__expf(m - b.x) + __expf(m - b.y)) + (__expf(m - b.z) + __expf(m - b.w)));
#pragma unroll
        for (int off = 32; off > 0; off >>= 1) s += __shfl_xor(s, off);
        if (ln == 0) {
            lds[4096 + wv] = m;                  // row min
            lds[4104 + wv] = 1.f / s;            // row inv-sum
        }
    }
    __syncthreads();

    // ---- final: exp(mn - d) * inv from registers, coalesced 2 KB stores
#pragma unroll
    for (int rr = 0; rr < RPB; rr++) {
        float mn  = lds[4096 + rr];              // broadcast (same address)
        float inv = lds[4104 + rr];
        out[(size_t)(r0 + rr) * M_CONS + tid] = __expf(mn - d[rr]) * inv;
    }
}

extern "C" void kernel_launch(void* const* d_in, const int* in_sizes, int n_in,
                              void* d_out, int out_size, void* d_ws, size_t ws_size,
                              hipStream_t stream) {
    const float* sites = (const float*)d_in[0];
    const float* cons  = (const float*)d_in[1];
    float* out = (float*)d_out;

    fused_kernel<<<N_SITES / RPB, 512, 0, stream>>>(sites, cons, out);  // 512 blocks
}